// Round 19
// baseline (27.201 us; speedup 1.0000x reference)
//
#include <hip/hip_runtime.h>
#include <math.h>

#define HW (1024*1024)
#define BATCH 16

// Kernel 1: per-(batch,channel) complex affine params -> d_ws (768 B).
// Fold: caddmul(clerp(w0,w1,l), s, bias) = w0*s*(1-l) + w1*s*l + bias,
// so A = s*(1-l), B = s*l, C = bias.  par: [16][2][6] = {Ar,Ai,Br,Bi,Cr,Ci}
__global__ __launch_bounds__(192) void params_kernel(
    const float* __restrict__ x,       // [16][64]
    const float* __restrict__ W_in,    // [12][64]
    const float* __restrict__ b_in,    // [12]
    const float* __restrict__ W_gate,  // [12][64]
    const float* __restrict__ b_gate,  // [12]
    float* __restrict__ par)           // [16][2][6]
{
    __shared__ float smod[BATCH][12];
    int t = threadIdx.x;
    int b = t / 12, j = t % 12;
    {
        const float4* x4  = (const float4*)(x + b * 64);
        const float4* wi4 = (const float4*)(W_in + j * 64);
        const float4* wg4 = (const float4*)(W_gate + j * 64);
        float xt = b_in[j], xg = b_gate[j];
#pragma unroll
        for (int k = 0; k < 16; ++k) {
            float4 xv = x4[k], wi = wi4[k], wg = wg4[k];
            xt = fmaf(xv.x, wi.x, xt); xg = fmaf(xv.x, wg.x, xg);
            xt = fmaf(xv.y, wi.y, xt); xg = fmaf(xv.y, wg.y, xg);
            xt = fmaf(xv.z, wi.z, xt); xg = fmaf(xv.z, wg.z, xg);
            xt = fmaf(xv.w, wi.w, xt); xg = fmaf(xv.w, wg.w, xg);
        }
        smod[b][j] = xt * tanhf(xg);
    }
    __syncthreads();
    if (t < 32) {
        int bb = t >> 1, c = t & 1;
        float l0 = smod[bb][0 + c * 2 + 0] + 0.5f;
        float l1 = smod[bb][0 + c * 2 + 1];
        float br = smod[bb][4 + c * 2 + 0];
        float bi = smod[bb][4 + c * 2 + 1];
        float s0 = smod[bb][8 + c * 2 + 0] + 1.0f;
        float s1 = smod[bb][8 + c * 2 + 1];
        float omr = 1.0f - l0, omi = -l1;      // (1 - l)
        float Ar = s0 * omr - s1 * omi;
        float Ai = s0 * omi + s1 * omr;
        float Br = s0 * l0 - s1 * l1;
        float Bi = s0 * l1 + s1 * l0;
        float* p = par + (bb * 2 + c) * 6;
        p[0] = Ar; p[1] = Ai; p[2] = Br; p[3] = Bi; p[4] = br; p[5] = bi;
    }
}

// Kernel 2: streaming transform, 1 px/thread, 4096 blocks = 2 GRID
// GENERATIONS (residency ~2048 blocks): generation-2 read bursts overlap
// generation-1 compute/store phases, interleaving the 32 MB read stream
// with the 64 MB nt write stream instead of front-loading all reads.
// nt stores (R18: -1.4us, L2 write-allocate bypass) retained.
__global__ __launch_bounds__(256) void main_kernel(
    const float* __restrict__ wts,   // [2][2][HW][2]
    const float* __restrict__ par,   // [16][2][6] = 192 floats
    float* __restrict__ out)         // [16][HW]
{
    const int idx = blockIdx.x * 256 + threadIdx.x;   // 0 .. HW-1 (1 px)
    const float2* w2 = (const float2*)wts;            // [jc][HW] float2s

    float2 W00 = w2[0 * HW + idx];   // j=0, c=0  (re, im)
    float2 W01 = w2[1 * HW + idx];   // j=0, c=1
    float2 W10 = w2[2 * HW + idx];   // j=1, c=0
    float2 W11 = w2[3 * HW + idx];   // j=1, c=1

#pragma unroll
    for (int b = 0; b < BATCH; ++b) {
        // uniform indices -> s_load from constant cache, hoisted
        const float* p0 = par + (b * 2 + 0) * 6;
        const float* p1 = par + (b * 2 + 1) * 6;
        float A0r = p0[0], A0i = p0[1], B0r = p0[2], B0i = p0[3], c0r = p0[4], c0i = p0[5];
        float A1r = p1[0], A1i = p1[1], B1r = p1[2], B1i = p1[3], c1r = p1[4], c1i = p1[5];

        float z0r = c0r + A0r * W00.x - A0i * W00.y + B0r * W10.x - B0i * W10.y;
        float z0i = c0i + A0r * W00.y + A0i * W00.x + B0r * W10.y + B0i * W10.x;
        float z1r = c1r + A1r * W01.x - A1i * W01.y + B1r * W11.x - B1i * W11.y;
        float z1i = c1i + A1r * W01.y + A1i * W01.x + B1r * W11.y + B1i * W11.x;
        // raw v_rsq_f32 (validated R16/R17: absmax unchanged at 3.9e-3)
        float rs = __builtin_amdgcn_rsqf(z1r * z1r + z1i * z1i + 1e-12f);
        float o  = (z0r * z1r + z0i * z1i) * rs;
        __builtin_nontemporal_store(o, &out[b * HW + idx]);
    }
}

extern "C" void kernel_launch(void* const* d_in, const int* in_sizes, int n_in,
                              void* d_out, int out_size, void* d_ws, size_t ws_size,
                              hipStream_t stream) {
    const float* x      = (const float*)d_in[0];
    const float* W_in   = (const float*)d_in[1];
    const float* b_in   = (const float*)d_in[2];
    const float* W_gate = (const float*)d_in[3];
    const float* b_gate = (const float*)d_in[4];
    const float* wts    = (const float*)d_in[5];
    float* out = (float*)d_out;
    float* par = (float*)d_ws;

    params_kernel<<<1, 192, 0, stream>>>(x, W_in, b_in, W_gate, b_gate, par);
    main_kernel<<<4096, 256, 0, stream>>>(wts, par, out);
}